// Round 3
// baseline (256.287 us; speedup 1.0000x reference)
//
#include <hip/hip_runtime.h>
#include <math.h>

// ---- problem constants (fixed by reference) ----
constexpr int kD        = 2048;   // model dim
constexpr int kE        = 64;     // experts
constexpr int kWaves    = 8;      // waves per block (512 threads)
constexpr int kBlockTok = 64;     // tokens per block
constexpr int kKpw      = kD / kWaves;   // 256  k-range per wave
constexpr int kBK       = 16;     // k-tile staged per iteration
constexpr int kTiles    = kKpw / kBK;    // 16
// stride 20 floats = 80 B: multiple of 16 B (ds_*_b128 alignment!) and
// row*20 mod 32 hits 8 distinct banks -> conflict-free staging/stats.
constexpr int kXsStride = 20;
constexpr int kBufStride = kE + 2;       // 66 (scalar access only)

// ---------------------------------------------------------------------------
// Prep: per-expert row-sum S_e = sum_k p[e][k] and inv_norm_e = 1/max(||p_e||,1e-8)
// ws[0..63] = S, ws[64..127] = inv_norm
// ---------------------------------------------------------------------------
__global__ __launch_bounds__(256) void proto_prep(const float* __restrict__ p,
                                                  float* __restrict__ ws) {
  const int e   = blockIdx.x;
  const int tid = threadIdx.x;
  const float4* row = (const float4*)(p + (size_t)e * kD);
  float s = 0.f, q = 0.f;
  for (int j = tid; j < kD / 4; j += 256) {
    float4 v = row[j];
    s += (v.x + v.y) + (v.z + v.w);
    q = fmaf(v.x, v.x, fmaf(v.y, v.y, fmaf(v.z, v.z, fmaf(v.w, v.w, q))));
  }
  #pragma unroll
  for (int off = 32; off >= 1; off >>= 1) {
    s += __shfl_xor(s, off, 64);
    q += __shfl_xor(q, off, 64);
  }
  __shared__ float as[4], aq[4];
  if ((tid & 63) == 0) { as[tid >> 6] = s; aq[tid >> 6] = q; }
  __syncthreads();
  if (tid == 0) {
    float S = (as[0] + as[1]) + (as[2] + as[3]);
    float Q = (aq[0] + aq[1]) + (aq[2] + aq[3]);
    float n = fmaxf(sqrtf(Q), 1e-8f);
    ws[e]      = S;
    ws[kE + e] = 1.f / n;
  }
}

// ---------------------------------------------------------------------------
// Main fused kernel: raw GEMM x·p^T (K-split over 8 waves) + per-token stats,
// cross-wave combine in LDS, LN/unit-norm folded into epilogue, top-2 select.
// ---------------------------------------------------------------------------
__global__ __launch_bounds__(512, 2) void router_main(
    const float* __restrict__ x, const float* __restrict__ p,
    const float* __restrict__ ws, float* __restrict__ out_w,
    float* __restrict__ out_i) {
  __shared__ float xs_all[kWaves][kBlockTok][kXsStride];  // 40960 B
  __shared__ float buf[kBlockTok * kBufStride];           // 16896 B
  __shared__ float sSx[kWaves][kBlockTok];                //  2048 B
  __shared__ float sSxx[kWaves][kBlockTok];               //  2048 B  -> 61952 B total

  const int w    = threadIdx.x >> 6;   // wave id (k-slice owner)
  const int lane = threadIdx.x & 63;
  const int tt   = lane & 7;           // token-thread
  const int te   = lane >> 3;          // expert-thread
  const int tok0 = blockIdx.x * kBlockTok;

  const float* xw = x + (size_t)tok0 * kD + w * kKpw;
  const float* pw = p + w * kKpw;
  float* xs = &xs_all[w][0][0];

  float acc[8][8];
  #pragma unroll
  for (int i = 0; i < 8; ++i)
    #pragma unroll
    for (int j = 0; j < 8; ++j) acc[i][j] = 0.f;
  float sx = 0.f, sxx = 0.f;

  for (int kt = 0; kt < kTiles; ++kt) {
    const float* gsrc = xw + kt * kBK;
    // stage 64 tokens x 16 k (4 float4 per lane), coalesced 128B segments
    #pragma unroll
    for (int jj = 0; jj < 4; ++jj) {
      int f = lane + 64 * jj;          // 0..255 float4 index
      int row = f >> 2;
      int c4  = f & 3;
      float4 v = *(const float4*)(gsrc + (size_t)row * kD + c4 * 4);
      *(float4*)(xs + row * kXsStride + c4 * 4) = v;   // 80B row stride: 16B-aligned
    }
    // per-token LN stats partials from LDS (lane == local token); x read from HBM once
    #pragma unroll
    for (int j = 0; j < 4; ++j) {
      float4 v = *(const float4*)(xs + lane * kXsStride + j * 4);
      sx += (v.x + v.y) + (v.z + v.w);
      sxx = fmaf(v.x, v.x, fmaf(v.y, v.y, fmaf(v.z, v.z, fmaf(v.w, v.w, sxx))));
    }
    const float* pt = pw + kt * kBK;
    #pragma unroll
    for (int k4 = 0; k4 < 4; ++k4) {
      float4 pf[8];
      #pragma unroll
      for (int j = 0; j < 8; ++j)   // prototypes direct from global (L2-resident)
        pf[j] = *(const float4*)(pt + (size_t)(te + 8 * j) * kD + k4 * 4);
      float4 xf[8];
      #pragma unroll
      for (int i = 0; i < 8; ++i)
        xf[i] = *(const float4*)(xs + (tt + 8 * i) * kXsStride + k4 * 4);
      #pragma unroll
      for (int i = 0; i < 8; ++i)
        #pragma unroll
        for (int j = 0; j < 8; ++j) {
          acc[i][j] = fmaf(xf[i].x, pf[j].x, acc[i][j]);
          acc[i][j] = fmaf(xf[i].y, pf[j].y, acc[i][j]);
          acc[i][j] = fmaf(xf[i].z, pf[j].z, acc[i][j]);
          acc[i][j] = fmaf(xf[i].w, pf[j].w, acc[i][j]);
        }
    }
  }

  sSx[w][lane]  = sx;   // lane = local token
  sSxx[w][lane] = sxx;

  // cross-wave K-partial combine: 8 barriered phases into one LDS tile
  for (int ph = 0; ph < kWaves; ++ph) {
    __syncthreads();
    if (w == ph) {
      #pragma unroll
      for (int i = 0; i < 8; ++i)
        #pragma unroll
        for (int j = 0; j < 8; ++j) {
          float* dst = &buf[(tt + 8 * i) * kBufStride + (te + 8 * j)];
          if (ph == 0) *dst = acc[i][j];
          else         *dst += acc[i][j];
        }
    }
  }
  __syncthreads();

  // epilogue: wave w handles tokens [w*8, w*8+8), lane = expert
  const float Se  = ws[lane];
  const float inv = ws[kE + lane];
  #pragma unroll
  for (int tl = 0; tl < 8; ++tl) {
    int t = w * 8 + tl;
    float Sx = 0.f, Sq = 0.f;
    #pragma unroll
    for (int q = 0; q < kWaves; ++q) { Sx += sSx[q][t]; Sq += sSxx[q][t]; }
    float mu   = Sx * (1.f / kD);
    float var  = Sq * (1.f / kD) - mu * mu;
    float rstd = rsqrtf(var + 1e-5f);
    float Dv   = buf[t * kBufStride + lane];
    // LN + unit-norm + temperature folded: logit_e = rstd*(D - mu*S_e)*inv_e / 8
    float logit = (Dv - mu * Se) * rstd * inv * 0.125f;

    // top-1 (value desc, index asc on ties — matches jax.lax.top_k)
    float v1 = logit; int i1 = lane;
    #pragma unroll
    for (int off = 32; off >= 1; off >>= 1) {
      float ov = __shfl_xor(v1, off, 64);
      int   oi = __shfl_xor(i1, off, 64);
      if (ov > v1 || (ov == v1 && oi < i1)) { v1 = ov; i1 = oi; }
    }
    // top-2: mask the winner, repeat
    float ml = (lane == i1) ? -3.402823466e38f : logit;
    float v2 = ml; int i2 = lane;
    #pragma unroll
    for (int off = 32; off >= 1; off >>= 1) {
      float ov = __shfl_xor(v2, off, 64);
      int   oi = __shfl_xor(i2, off, 64);
      if (ov > v2 || (ov == v2 && oi < i2)) { v2 = ov; i2 = oi; }
    }
    if (lane == 0) {
      int tg = tok0 + t;
      // softmax + top-2 renorm collapses: [1, e^{l2-l1}] / (1 + e^{l2-l1})
      float er = expf(v2 - v1);
      float r  = 1.f / (1.f + er);
      out_w[2 * tg]     = r;
      out_w[2 * tg + 1] = er * r;
      // harness reads the WHOLE out buffer as float32 -> indices as float values
      out_i[2 * tg]     = (float)i1;
      out_i[2 * tg + 1] = (float)i2;
    }
  }
}

extern "C" void kernel_launch(void* const* d_in, const int* in_sizes, int n_in,
                              void* d_out, int out_size, void* d_ws, size_t ws_size,
                              hipStream_t stream) {
  const float* x = (const float*)d_in[0];   // [4,4096,2048] fp32
  const float* p = (const float*)d_in[1];   // [64,2048] fp32
  float* ws = (float*)d_ws;                 // 128 floats: S_e, inv_norm_e
  const int T = in_sizes[0] / kD;           // 16384 tokens
  float* out_w = (float*)d_out;             // [T,2] fp32 weights
  float* out_i = (float*)d_out + (size_t)T * 2;  // [T,2] indices AS FLOAT VALUES

  proto_prep<<<kE, 256, 0, stream>>>(p, ws);
  router_main<<<T / kBlockTok, 512, 0, stream>>>(x, p, ws, out_w, out_i);
}

// Round 4
// 225.543 us; speedup vs baseline: 1.1363x; 1.1363x over previous
//
#include <hip/hip_runtime.h>
#include <math.h>

typedef __attribute__((ext_vector_type(8))) short short8;   // 8 bf16 (4 VGPRs)
typedef __attribute__((ext_vector_type(4))) float f32x4;    // MFMA accumulator

constexpr int kD   = 2048;
constexpr int kE   = 64;
constexpr int kM   = 32;          // tokens per block
constexpr int kBK  = 128;         // K per staging iteration
constexpr int kIt  = kD / kBK;    // 16
constexpr int kLds = 136;         // ushort row stride (272 B: 16B-aligned, bank-uniform)

// ---------------------------------------------------------------------------
// Prep: per-expert S_e = sum_k p[e][k], inv_norm_e = 1/max(||p_e||,1e-8)
// ---------------------------------------------------------------------------
__global__ __launch_bounds__(256) void proto_prep(const float* __restrict__ p,
                                                  float* __restrict__ ws) {
  const int e   = blockIdx.x;
  const int tid = threadIdx.x;
  const float4* row = (const float4*)(p + (size_t)e * kD);
  float s = 0.f, q = 0.f;
  for (int j = tid; j < kD / 4; j += 256) {
    float4 v = row[j];
    s += (v.x + v.y) + (v.z + v.w);
    q = fmaf(v.x, v.x, fmaf(v.y, v.y, fmaf(v.z, v.z, fmaf(v.w, v.w, q))));
  }
  #pragma unroll
  for (int off = 32; off >= 1; off >>= 1) {
    s += __shfl_xor(s, off, 64);
    q += __shfl_xor(q, off, 64);
  }
  __shared__ float as[4], aq[4];
  if ((tid & 63) == 0) { as[tid >> 6] = s; aq[tid >> 6] = q; }
  __syncthreads();
  if (tid == 0) {
    float S = (as[0] + as[1]) + (as[2] + as[3]);
    float Q = (aq[0] + aq[1]) + (aq[2] + aq[3]);
    ws[e]      = S;
    ws[kE + e] = 1.f / fmaxf(sqrtf(Q), 1e-8f);
  }
}

// 3-limb truncated bf16 split: v = h + m + l + O(2^-24 |v|)
__device__ __forceinline__ void split3(float v, unsigned& h, unsigned& m, unsigned& l) {
  unsigned u = __float_as_uint(v);
  h = u & 0xFFFF0000u;
  float r1 = v - __uint_as_float(h);
  m = __float_as_uint(r1) & 0xFFFF0000u;
  float r2 = r1 - __uint_as_float(m);
  l = __float_as_uint(r2);                 // top 16 bits used
}

// pack limbs of two consecutive elements into one dword per plane
__device__ __forceinline__ void pack2(float e0, float e1,
                                      unsigned& dh, unsigned& dm, unsigned& dl) {
  unsigned h0, m0, l0, h1, m1, l1;
  split3(e0, h0, m0, l0);
  split3(e1, h1, m1, l1);
  dh = (h0 >> 16) | h1;                    // h1 low 16 already zero
  dm = (m0 >> 16) | m1;
  dl = (l0 >> 16) | (l1 & 0xFFFF0000u);
}

union FragU { short8 s; unsigned u[4]; };

// ---------------------------------------------------------------------------
// Main: MFMA GEMM x·p^T via 3-limb bf16 (6 products), LN/unit-norm/temp folded
// into epilogue, collapsed softmax + top-2.  32 tokens/block, 4 waves N-split.
// ---------------------------------------------------------------------------
__global__ __launch_bounds__(256, 2) void router_main(
    const float* __restrict__ x, const float* __restrict__ p,
    const float* __restrict__ ws, float* __restrict__ out_w,
    float* __restrict__ out_i) {
  __shared__ unsigned short sXh[kM * kLds];   // 8704 B per plane
  __shared__ unsigned short sXm[kM * kLds];
  __shared__ unsigned short sXl[kM * kLds];
  __shared__ float sLogit[kM * 68];           // 8704 B
  __shared__ float sStats[kM][2];             //  256 B   -> ~35 KB total

  const int t    = threadIdx.x;
  const int w    = t >> 6;          // wave id: experts 16w..16w+16
  const int lane = t & 63;
  const int ln15 = lane & 15;
  const int q    = lane >> 4;       // MFMA k-octet selector
  const int tok0 = blockIdx.x * kM;

  const float* xg = x + (size_t)tok0 * kD;
  const int pe = w * 16 + ln15;     // this lane's expert row for B frags

  f32x4 acc[2];
  acc[0] = (f32x4){0.f, 0.f, 0.f, 0.f};
  acc[1] = (f32x4){0.f, 0.f, 0.f, 0.f};
  float sx[4] = {0.f, 0.f, 0.f, 0.f}, sxx[4] = {0.f, 0.f, 0.f, 0.f};

  // prefetch iter 0:  thread t, slice j: flat float4 f = t + 256j,
  // row = f>>5 (32 f4 per row), col4 = f&31  — fully coalesced
  float4 pf[4];
  #pragma unroll
  for (int j = 0; j < 4; ++j) {
    int f = t + 256 * j;
    pf[j] = *(const float4*)(xg + (size_t)(f >> 5) * kD + (f & 31) * 4);
  }

  for (int it = 0; it < kIt; ++it) {
    __syncthreads();                 // previous iter's frag reads done
    #pragma unroll
    for (int j = 0; j < 4; ++j) {
      int f   = t + 256 * j;
      int row = f >> 5, c4 = f & 31;
      float4 v = pf[j];
      sx[j] += (v.x + v.y) + (v.z + v.w);
      sxx[j] = fmaf(v.x, v.x, fmaf(v.y, v.y, fmaf(v.z, v.z, fmaf(v.w, v.w, sxx[j]))));
      unsigned dh0, dm0, dl0, dh1, dm1, dl1;
      pack2(v.x, v.y, dh0, dm0, dl0);
      pack2(v.z, v.w, dh1, dm1, dl1);
      int off = row * kLds + c4 * 4;             // ushort offset, 8B-aligned
      *(uint2*)&sXh[off] = make_uint2(dh0, dh1);
      *(uint2*)&sXm[off] = make_uint2(dm0, dm1);
      *(uint2*)&sXl[off] = make_uint2(dl0, dl1);
    }
    __syncthreads();
    if (it + 1 < kIt) {                          // prefetch next staging tile
      #pragma unroll
      for (int j = 0; j < 4; ++j) {
        int f = t + 256 * j;
        pf[j] = *(const float4*)(xg + (size_t)(f >> 5) * kD + (it + 1) * kBK + (f & 31) * 4);
      }
    }
    // compute: 4 chunks of K=32
    #pragma unroll
    for (int c = 0; c < 4; ++c) {
      const float* pb = p + (size_t)pe * kD + it * kBK + c * 32 + q * 8;
      float4 b0 = *(const float4*)(pb);
      float4 b1 = *(const float4*)(pb + 4);
      FragU bh, bm, bl;
      pack2(b0.x, b0.y, bh.u[0], bm.u[0], bl.u[0]);
      pack2(b0.z, b0.w, bh.u[1], bm.u[1], bl.u[1]);
      pack2(b1.x, b1.y, bh.u[2], bm.u[2], bl.u[2]);
      pack2(b1.z, b1.w, bh.u[3], bm.u[3], bl.u[3]);
      #pragma unroll
      for (int m = 0; m < 2; ++m) {
        int ro = (m * 16 + ln15) * kLds + c * 32 + q * 8;   // ushort off, 16B-aligned
        short8 ah = *(const short8*)&sXh[ro];
        short8 am = *(const short8*)&sXm[ro];
        short8 al = *(const short8*)&sXl[ro];
        // 6 limb products: hh, hm, mh, mm, hl, lh  (dropped terms <= 2^-24)
        acc[m] = __builtin_amdgcn_mfma_f32_16x16x32_bf16(ah, bh.s, acc[m], 0, 0, 0);
        acc[m] = __builtin_amdgcn_mfma_f32_16x16x32_bf16(ah, bm.s, acc[m], 0, 0, 0);
        acc[m] = __builtin_amdgcn_mfma_f32_16x16x32_bf16(am, bh.s, acc[m], 0, 0, 0);
        acc[m] = __builtin_amdgcn_mfma_f32_16x16x32_bf16(am, bm.s, acc[m], 0, 0, 0);
        acc[m] = __builtin_amdgcn_mfma_f32_16x16x32_bf16(ah, bl.s, acc[m], 0, 0, 0);
        acc[m] = __builtin_amdgcn_mfma_f32_16x16x32_bf16(al, bh.s, acc[m], 0, 0, 0);
      }
    }
  }

  // LN stats: reduce each j-partial over its 32-thread half-wave row group
  #pragma unroll
  for (int j = 0; j < 4; ++j) {
    float a = sx[j], b = sxx[j];
    #pragma unroll
    for (int off = 16; off >= 1; off >>= 1) {
      a += __shfl_xor(a, off, 64);
      b += __shfl_xor(b, off, 64);
    }
    if ((lane & 31) == 0) {
      int row = (t >> 5) + 8 * j;
      sStats[row][0] = a;
      sStats[row][1] = b;
    }
  }

  // raw dot -> LDS  (C layout: row=(lane>>4)*4+i, col=lane&15)
  #pragma unroll
  for (int m = 0; m < 2; ++m)
    #pragma unroll
    for (int i = 0; i < 4; ++i) {
      int tok = m * 16 + q * 4 + i;
      sLogit[tok * 68 + w * 16 + ln15] = acc[m][i];
    }
  __syncthreads();

  // epilogue: wave w -> tokens 8w..8w+8, lane = expert
  const float Se  = ws[lane];
  const float inv = ws[kE + lane];
  #pragma unroll
  for (int tl = 0; tl < 8; ++tl) {
    int tk = w * 8 + tl;
    float Sx = sStats[tk][0], Sq = sStats[tk][1];
    float mu   = Sx * (1.f / kD);
    float var  = Sq * (1.f / kD) - mu * mu;
    float rstd = rsqrtf(var + 1e-5f);
    float logit = (sLogit[tk * 68 + lane] - mu * Se) * rstd * inv * 0.125f;

    float v1 = logit; int i1 = lane;
    #pragma unroll
    for (int off = 32; off >= 1; off >>= 1) {
      float ov = __shfl_xor(v1, off, 64);
      int   oi = __shfl_xor(i1, off, 64);
      if (ov > v1 || (ov == v1 && oi < i1)) { v1 = ov; i1 = oi; }
    }
    float ml = (lane == i1) ? -3.402823466e38f : logit;
    float v2 = ml; int i2 = lane;
    #pragma unroll
    for (int off = 32; off >= 1; off >>= 1) {
      float ov = __shfl_xor(v2, off, 64);
      int   oi = __shfl_xor(i2, off, 64);
      if (ov > v2 || (ov == v2 && oi < i2)) { v2 = ov; i2 = oi; }
    }
    if (lane == 0) {
      int tg = tok0 + tk;
      float er = expf(v2 - v1);
      float r  = 1.f / (1.f + er);
      out_w[2 * tg]     = r;
      out_w[2 * tg + 1] = er * r;
      out_i[2 * tg]     = (float)i1;   // harness reads whole buffer as f32
      out_i[2 * tg + 1] = (float)i2;
    }
  }
}

extern "C" void kernel_launch(void* const* d_in, const int* in_sizes, int n_in,
                              void* d_out, int out_size, void* d_ws, size_t ws_size,
                              hipStream_t stream) {
  const float* x = (const float*)d_in[0];   // [4,4096,2048] fp32
  const float* p = (const float*)d_in[1];   // [64,2048] fp32
  float* ws = (float*)d_ws;                 // 128 floats
  const int T = in_sizes[0] / kD;           // 16384 tokens
  float* out_w = (float*)d_out;
  float* out_i = (float*)d_out + (size_t)T * 2;

  proto_prep<<<kE, 256, 0, stream>>>(p, ws);
  router_main<<<T / kM, 256, 0, stream>>>(x, p, ws, out_w, out_i);
}

// Round 5
// 225.233 us; speedup vs baseline: 1.1379x; 1.0014x over previous
//
#include <hip/hip_runtime.h>
#include <math.h>

typedef __attribute__((ext_vector_type(8))) short short8;   // 8 bf16 (4 VGPRs)
typedef __attribute__((ext_vector_type(4))) float f32x4;    // MFMA accumulator

constexpr int kD  = 2048;
constexpr int kE  = 64;
constexpr int kM  = 16;          // tokens per block -> 1024 blocks -> 4/CU
constexpr int kBK = 128;         // K per staging iteration
constexpr int kIt = kD / kBK;    // 16
// A-limb LDS, fragment order: addr = c*kCS + L*48 + (L>>4)*16 + plane*16 + j*2
// (o-pad +16B per octet group rotates banks; reads: 8-lane phases hit all 32
//  banks exactly once; staging writes: 2-way max = free)
constexpr int kCS = 3136;        // chunk stride bytes (>= 48*64 + 16*3 + 48)

// p limbs pre-converted to MFMA B-fragment order:
// g_B[plane][e0=e>>4][gc=k>>5][L=16*((k>>3)&3)+(e&15)][j=k&7]   (ushorts)
constexpr int kPlaneU = 4 * 64 * 512;   // 131072 ushorts per plane
__device__ unsigned short g_B[3 * kPlaneU];   // 786 KB

// 3-limb truncated bf16 split: v = h + m + l + O(2^-24 |v|)
__device__ __forceinline__ void split3(float v, unsigned& h, unsigned& m, unsigned& l) {
  unsigned u = __float_as_uint(v);
  h = u & 0xFFFF0000u;
  float r1 = v - __uint_as_float(h);
  m = __float_as_uint(r1) & 0xFFFF0000u;
  float r2 = r1 - __uint_as_float(m);
  l = __float_as_uint(r2);
}

// pack limbs of two consecutive elements into one dword per plane
__device__ __forceinline__ void pack2(float e0, float e1,
                                      unsigned& dh, unsigned& dm, unsigned& dl) {
  unsigned h0, m0, l0, h1, m1, l1;
  split3(e0, h0, m0, l0);
  split3(e1, h1, m1, l1);
  dh = (h0 >> 16) | h1;
  dm = (m0 >> 16) | m1;
  dl = (l0 >> 16) | (l1 & 0xFFFF0000u);
}

// ---------------------------------------------------------------------------
// Prep: S_e, inv_norm_e into ws; p 3-limb bf16 into g_B in B-fragment order.
// block e: thread t owns k in [8t, 8t+8) = one full octet (gc = t>>2, o = t&3).
// ---------------------------------------------------------------------------
__global__ __launch_bounds__(256) void proto_prep(const float* __restrict__ p,
                                                  float* __restrict__ ws) {
  const int e = blockIdx.x, t = threadIdx.x;
  const float* row = p + (size_t)e * kD;
  float4 v0 = *(const float4*)(row + 8 * t);
  float4 v1 = *(const float4*)(row + 8 * t + 4);

  unsigned dh[4], dm[4], dl[4];
  pack2(v0.x, v0.y, dh[0], dm[0], dl[0]);
  pack2(v0.z, v0.w, dh[1], dm[1], dl[1]);
  pack2(v1.x, v1.y, dh[2], dm[2], dl[2]);
  pack2(v1.z, v1.w, dh[3], dm[3], dl[3]);
  const int gc = t >> 2, o = t & 3;
  size_t base = (size_t)((e >> 4) * 64 + gc) * 512 + (16 * o + (e & 15)) * 8;
  *(uint4*)&g_B[base]               = make_uint4(dh[0], dh[1], dh[2], dh[3]);
  *(uint4*)&g_B[kPlaneU + base]     = make_uint4(dm[0], dm[1], dm[2], dm[3]);
  *(uint4*)&g_B[2 * kPlaneU + base] = make_uint4(dl[0], dl[1], dl[2], dl[3]);

  float s = (v0.x + v0.y) + (v0.z + v0.w) + (v1.x + v1.y) + (v1.z + v1.w);
  float q = v0.x*v0.x + v0.y*v0.y + v0.z*v0.z + v0.w*v0.w
          + v1.x*v1.x + v1.y*v1.y + v1.z*v1.z + v1.w*v1.w;
  #pragma unroll
  for (int off = 32; off >= 1; off >>= 1) {
    s += __shfl_xor(s, off, 64);
    q += __shfl_xor(q, off, 64);
  }
  __shared__ float as[4], aq[4];
  if ((t & 63) == 0) { as[t >> 6] = s; aq[t >> 6] = q; }
  __syncthreads();
  if (t == 0) {
    float S = (as[0] + as[1]) + (as[2] + as[3]);
    float Q = (aq[0] + aq[1]) + (aq[2] + aq[3]);
    ws[e]      = S;
    ws[kE + e] = 1.f / fmaxf(sqrtf(Q), 1e-8f);
  }
}

// ---------------------------------------------------------------------------
// Main: 16 tokens/block, 4 waves n-split (16 experts each). A-limbs staged to
// fragment-ordered LDS; B-limbs loaded coalesced from g_B (L2-hot). 6 limb
// MFMAs. LN/unit-norm/temp folded into epilogue; collapsed softmax + top-2.
// ---------------------------------------------------------------------------
__global__ __launch_bounds__(256, 4) void router_main(
    const float* __restrict__ x, const float* __restrict__ ws,
    float* __restrict__ out_w, float* __restrict__ out_i) {
  __shared__ __align__(16) unsigned char sA[4 * kCS];   // 12544 B
  __shared__ float sLogit[kM * 68];                     //  4352 B
  __shared__ float sStats[kM][2];                       //   128 B

  const int t    = threadIdx.x;
  const int w    = t >> 6;          // wave: experts [16w, 16w+16)
  const int L    = t & 63;
  const int ln15 = L & 15;
  const int q    = L >> 4;
  const int tok0 = blockIdx.x * kM;
  const float* xg = x + (size_t)tok0 * kD;

  f32x4 acc = (f32x4){0.f, 0.f, 0.f, 0.f};
  float sx[2] = {0.f, 0.f}, sxx[2] = {0.f, 0.f};

  // staging slice jj: f = t + 256*jj; token m = f>>5; c4 = f&31; k = 4*c4
  float4 pf[2];
  #pragma unroll
  for (int jj = 0; jj < 2; ++jj) {
    int f = t + 256 * jj;
    pf[jj] = *(const float4*)(xg + (size_t)(f >> 5) * kD + (f & 31) * 4);
  }

  for (int it = 0; it < kIt; ++it) {
    __syncthreads();                 // previous iter's frag reads done
    #pragma unroll
    for (int jj = 0; jj < 2; ++jj) {
      int f = t + 256 * jj;
      int c4 = f & 31, k = 4 * c4;
      int m = f >> 5, c = k >> 5, o = (k >> 3) & 3, j = k & 7;
      float4 v = pf[jj];
      sx[jj] += (v.x + v.y) + (v.z + v.w);
      sxx[jj] = fmaf(v.x, v.x, fmaf(v.y, v.y, fmaf(v.z, v.z, fmaf(v.w, v.w, sxx[jj]))));
      unsigned dh0, dm0, dl0, dh1, dm1, dl1;
      pack2(v.x, v.y, dh0, dm0, dl0);
      pack2(v.z, v.w, dh1, dm1, dl1);
      unsigned char* dst = sA + c * kCS + (16 * o + m) * 48 + o * 16 + j * 2;
      *(uint2*)(dst)      = make_uint2(dh0, dh1);   // plane h
      *(uint2*)(dst + 16) = make_uint2(dm0, dm1);   // plane m
      *(uint2*)(dst + 32) = make_uint2(dl0, dl1);   // plane l
    }
    __syncthreads();
    if (it + 1 < kIt) {
      #pragma unroll
      for (int jj = 0; jj < 2; ++jj) {
        int f = t + 256 * jj;
        pf[jj] = *(const float4*)(xg + (size_t)(f >> 5) * kD + (it + 1) * kBK + (f & 31) * 4);
      }
    }
    #pragma unroll
    for (int c = 0; c < 4; ++c) {
      const int gc = it * 4 + c;
      const size_t bo = (size_t)(w * 64 + gc) * 512 + L * 8;
      short8 bh = *(const short8*)&g_B[bo];
      short8 bm = *(const short8*)&g_B[kPlaneU + bo];
      short8 bl = *(const short8*)&g_B[2 * kPlaneU + bo];
      const unsigned char* ra = sA + c * kCS + L * 48 + (L >> 4) * 16;
      short8 ah = *(const short8*)(ra);
      short8 am = *(const short8*)(ra + 16);
      short8 al = *(const short8*)(ra + 32);
      // 6 limb products: hh, hm, mh, mm, hl, lh  (dropped terms <= 2^-24)
      acc = __builtin_amdgcn_mfma_f32_16x16x32_bf16(ah, bh, acc, 0, 0, 0);
      acc = __builtin_amdgcn_mfma_f32_16x16x32_bf16(ah, bm, acc, 0, 0, 0);
      acc = __builtin_amdgcn_mfma_f32_16x16x32_bf16(am, bh, acc, 0, 0, 0);
      acc = __builtin_amdgcn_mfma_f32_16x16x32_bf16(am, bm, acc, 0, 0, 0);
      acc = __builtin_amdgcn_mfma_f32_16x16x32_bf16(ah, bl, acc, 0, 0, 0);
      acc = __builtin_amdgcn_mfma_f32_16x16x32_bf16(al, bh, acc, 0, 0, 0);
    }
  }

  // LN stats: reduce within each 32-lane (same-token-row) group
  #pragma unroll
  for (int jj = 0; jj < 2; ++jj) {
    float a = sx[jj], b = sxx[jj];
    #pragma unroll
    for (int off = 16; off >= 1; off >>= 1) {
      a += __shfl_xor(a, off, 64);
      b += __shfl_xor(b, off, 64);
    }
    if ((L & 31) == 0) {
      int m = (t >> 5) + 8 * jj;
      sStats[m][0] = a;
      sStats[m][1] = b;
    }
  }

  // raw dot -> LDS  (C layout: row(token) = q*4+i, col(expert) = ln15)
  #pragma unroll
  for (int i = 0; i < 4; ++i)
    sLogit[(q * 4 + i) * 68 + w * 16 + ln15] = acc[i];
  __syncthreads();

  // epilogue: wave w -> tokens [4w, 4w+4), lane = expert
  const float Se  = ws[L];
  const float inv = ws[kE + L];
  #pragma unroll
  for (int tl = 0; tl < 4; ++tl) {
    int tk = w * 4 + tl;
    float mu   = sStats[tk][0] * (1.f / kD);
    float var  = sStats[tk][1] * (1.f / kD) - mu * mu;
    float rstd = rsqrtf(var + 1e-5f);
    float logit = (sLogit[tk * 68 + L] - mu * Se) * rstd * inv * 0.125f;

    float v1 = logit; int i1 = L;
    #pragma unroll
    for (int off = 32; off >= 1; off >>= 1) {
      float ov = __shfl_xor(v1, off, 64);
      int   oi = __shfl_xor(i1, off, 64);
      if (ov > v1 || (ov == v1 && oi < i1)) { v1 = ov; i1 = oi; }
    }
    float ml = (L == i1) ? -3.402823466e38f : logit;
    float v2 = ml; int i2 = L;
    #pragma unroll
    for (int off = 32; off >= 1; off >>= 1) {
      float ov = __shfl_xor(v2, off, 64);
      int   oi = __shfl_xor(i2, off, 64);
      if (ov > v2 || (ov == v2 && oi < i2)) { v2 = ov; i2 = oi; }
    }
    if (L == 0) {
      int tg = tok0 + tk;
      float er = expf(v2 - v1);
      float r  = 1.f / (1.f + er);
      out_w[2 * tg]     = r;
      out_w[2 * tg + 1] = er * r;
      out_i[2 * tg]     = (float)i1;   // harness reads whole buffer as f32
      out_i[2 * tg + 1] = (float)i2;
    }
  }
}

extern "C" void kernel_launch(void* const* d_in, const int* in_sizes, int n_in,
                              void* d_out, int out_size, void* d_ws, size_t ws_size,
                              hipStream_t stream) {
  const float* x = (const float*)d_in[0];   // [4,4096,2048] fp32
  const float* p = (const float*)d_in[1];   // [64,2048] fp32
  float* ws = (float*)d_ws;                 // 128 floats
  const int T = in_sizes[0] / kD;           // 16384 tokens
  float* out_w = (float*)d_out;
  float* out_i = (float*)d_out + (size_t)T * 2;

  proto_prep<<<kE, 256, 0, stream>>>(p, ws);
  router_main<<<T / kM, 256, 0, stream>>>(x, ws, out_w, out_i);
}